// Round 1
// baseline (712.484 us; speedup 1.0000x reference)
//
#include <hip/hip_runtime.h>
#include <math.h>

#define N_GRAPHS 512

// ---- degree: deg[dst] += 1 per edge --------------------------------------
__global__ void k_deg(const int* __restrict__ dst, float* __restrict__ deg, int ne) {
    int i = blockIdx.x * blockDim.x + threadIdx.x;
    if (i < ne) atomicAdd(&deg[dst[i]], 1.0f);
}

// ---- dinv = (deg+1)^-0.5, invdeg = (deg+1)^-1 -----------------------------
__global__ void k_inv(const float* __restrict__ deg, float* __restrict__ dinv,
                      float* __restrict__ invdeg, int n) {
    int i = blockIdx.x * blockDim.x + threadIdx.x;
    if (i < n) {
        float d = deg[i] + 1.0f;
        dinv[i]   = 1.0f / sqrtf(d);
        invdeg[i] = 1.0f / d;
    }
}

// ---- h1[n,64] = x[n,10] @ W1[10,64] ---------------------------------------
__global__ void k_h1(const float* __restrict__ x, const float* __restrict__ W1,
                     float* __restrict__ h1, int n) {
    __shared__ float W1s[640];
    __shared__ float xs[4][10];
    for (int i = threadIdx.x; i < 640; i += 256) W1s[i] = W1[i];
    if (threadIdx.x < 40) {
        int ln = threadIdx.x / 10, k = threadIdx.x % 10;
        int nd = blockIdx.x * 4 + ln;
        xs[ln][k] = (nd < n) ? x[nd * 10 + k] : 0.0f;
    }
    __syncthreads();
    int nl = threadIdx.x >> 6, f = threadIdx.x & 63;
    int node = blockIdx.x * 4 + nl;
    if (node < n) {
        float s = 0.f;
#pragma unroll
        for (int k = 0; k < 10; ++k) s += xs[nl][k] * W1s[k * 64 + f];
        h1[(size_t)node * 64 + f] = s;
    }
}

// ---- agg1[dst,f] += h1[src,f] * dinv[src]*dinv[dst]  (64 feats) -----------
__global__ void k_agg1(const int* __restrict__ src, const int* __restrict__ dst,
                       const float* __restrict__ dinv, const float* __restrict__ h1,
                       float* __restrict__ agg1, int ne) {
    int e = blockIdx.x * 4 + (threadIdx.x >> 6);
    int f = threadIdx.x & 63;
    if (e < ne) {
        int s = src[e], d = dst[e];
        float norm = dinv[s] * dinv[d];
        atomicAdd(&agg1[(size_t)d * 64 + f], h1[(size_t)s * 64 + f] * norm);
    }
}

// ---- h2[n,32] = relu(agg1 + h1*invdeg + b1) @ W2[64,32] -------------------
__global__ void k_h2(const float* __restrict__ agg1, const float* __restrict__ h1,
                     const float* __restrict__ invdeg, const float* __restrict__ b1,
                     const float* __restrict__ W2, float* __restrict__ h2, int n) {
    __shared__ float W2s[64 * 32];
    __shared__ float ts[4][64];
    for (int i = threadIdx.x; i < 2048; i += 256) W2s[i] = W2[i];
    int nl = threadIdx.x >> 6, f = threadIdx.x & 63;
    int node = blockIdx.x * 4 + nl;
    if (node < n) {
        float v = agg1[(size_t)node * 64 + f] + h1[(size_t)node * 64 + f] * invdeg[node] + b1[f];
        ts[nl][f] = v > 0.f ? v : 0.f;
    } else if (nl < 4) {
        ts[nl][f] = 0.f;
    }
    __syncthreads();
    if (threadIdx.x < 128) {
        int nl2 = threadIdx.x >> 5, o = threadIdx.x & 31;
        int node2 = blockIdx.x * 4 + nl2;
        if (node2 < n) {
            float s = 0.f;
#pragma unroll
            for (int f2 = 0; f2 < 64; ++f2) s += ts[nl2][f2] * W2s[f2 * 32 + o];
            h2[(size_t)node2 * 32 + o] = s;
        }
    }
}

// ---- agg2[dst,f] += h2[src,f] * norm  (32 feats) --------------------------
__global__ void k_agg2(const int* __restrict__ src, const int* __restrict__ dst,
                       const float* __restrict__ dinv, const float* __restrict__ h2,
                       float* __restrict__ agg2, int ne) {
    int e = blockIdx.x * 8 + (threadIdx.x >> 5);
    int f = threadIdx.x & 31;
    if (e < ne) {
        int s = src[e], d = dst[e];
        float norm = dinv[s] * dinv[d];
        atomicAdd(&agg2[(size_t)d * 32 + f], h2[(size_t)s * 32 + f] * norm);
    }
}

// ---- pooled[batch[node],o] += relu(agg2 + h2*invdeg + b2) -----------------
__global__ void k_pool(const float* __restrict__ agg2, const float* __restrict__ h2,
                       const float* __restrict__ invdeg, const float* __restrict__ b2,
                       const int* __restrict__ batch, float* __restrict__ pooled, int n) {
    int node = blockIdx.x * 8 + (threadIdx.x >> 5);
    int o = threadIdx.x & 31;
    if (node < n) {
        float v = agg2[(size_t)node * 32 + o] + h2[(size_t)node * 32 + o] * invdeg[node] + b2[o];
        v = v > 0.f ? v : 0.f;
        atomicAdd(&pooled[(size_t)batch[node] * 32 + o], v);
    }
}

// ---- out[g] = sigmoid(pooled[g,:] @ Wfc + bfc) ----------------------------
__global__ void k_fc(const float* __restrict__ pooled, const float* __restrict__ Wfc,
                     const float* __restrict__ bfc, float* __restrict__ out) {
    int g = blockIdx.x * blockDim.x + threadIdx.x;
    if (g < N_GRAPHS) {
        float s = bfc[0];
#pragma unroll
        for (int o = 0; o < 32; ++o) s += pooled[g * 32 + o] * Wfc[o];
        out[g] = 1.0f / (1.0f + expf(-s));
    }
}

extern "C" void kernel_launch(void* const* d_in, const int* in_sizes, int n_in,
                              void* d_out, int out_size, void* d_ws, size_t ws_size,
                              hipStream_t stream) {
    const int n  = in_sizes[0] / 10;   // 100000 nodes
    const int ne = in_sizes[1] / 2;    // 1600000 edges

    const float* x     = (const float*)d_in[0];
    const int*   ei    = (const int*)d_in[1];
    const int*   batch = (const int*)d_in[2];
    const float* W1    = (const float*)d_in[3];
    const float* b1    = (const float*)d_in[4];
    const float* W2    = (const float*)d_in[5];
    const float* b2    = (const float*)d_in[6];
    const float* Wfc   = (const float*)d_in[7];
    const float* bfc   = (const float*)d_in[8];
    const int* srcp = ei;
    const int* dstp = ei + ne;

    // workspace layout (floats)
    float* ws     = (float*)d_ws;
    float* deg    = ws;                        // n
    float* dinv   = deg + n;                   // n
    float* invdeg = dinv + n;                  // n
    float* h1     = invdeg + n;                // n*64
    float* agg1   = h1 + (size_t)n * 64;       // n*64
    float* h2     = agg1 + (size_t)n * 64;     // n*32
    float* pooled = h2 + (size_t)n * 32;       // 512*32
    float* agg2   = h1;                        // reuse h1 (dead after k_h2)

    hipMemsetAsync(deg,    0, (size_t)n * sizeof(float), stream);
    hipMemsetAsync(agg1,   0, (size_t)n * 64 * sizeof(float), stream);
    hipMemsetAsync(pooled, 0, (size_t)N_GRAPHS * 32 * sizeof(float), stream);

    k_deg <<<(ne + 255) / 256, 256, 0, stream>>>(dstp, deg, ne);
    k_inv <<<(n + 255) / 256, 256, 0, stream>>>(deg, dinv, invdeg, n);
    k_h1  <<<(n + 3) / 4,     256, 0, stream>>>(x, W1, h1, n);
    k_agg1<<<(ne + 3) / 4,    256, 0, stream>>>(srcp, dstp, dinv, h1, agg1, ne);
    k_h2  <<<(n + 3) / 4,     256, 0, stream>>>(agg1, h1, invdeg, b1, W2, h2, n);

    hipMemsetAsync(agg2, 0, (size_t)n * 32 * sizeof(float), stream);

    k_agg2<<<(ne + 7) / 8,    256, 0, stream>>>(srcp, dstp, dinv, h2, agg2, ne);
    k_pool<<<(n + 7) / 8,     256, 0, stream>>>(agg2, h2, invdeg, b2, batch, pooled, n);
    k_fc  <<<2,               256, 0, stream>>>(pooled, Wfc, bfc, (float*)d_out);
}

// Round 2
// 358.546 us; speedup vs baseline: 1.9871x; 1.9871x over previous
//
#include <hip/hip_runtime.h>
#include <math.h>

#define N_GRAPHS 512
#define SCAN_BS 256
#define SCAN_ITEMS 4

// ---- 1) histogram of dst (int atomics, 400 KB table) ----------------------
__global__ void k_hist(const int* __restrict__ dst, int* __restrict__ cnt, int ne) {
    int i = blockIdx.x * blockDim.x + threadIdx.x;
    if (i < ne) atomicAdd(&cnt[dst[i]], 1);
}

// ---- 2a) per-block sums for scan ------------------------------------------
__global__ void k_scanA(const int* __restrict__ cnt, int* __restrict__ partials, int n) {
    __shared__ int sh[SCAN_BS];
    int base = blockIdx.x * SCAN_BS * SCAN_ITEMS + threadIdx.x * SCAN_ITEMS;
    int s = 0;
#pragma unroll
    for (int k = 0; k < SCAN_ITEMS; ++k) { int i = base + k; if (i < n) s += cnt[i]; }
    sh[threadIdx.x] = s; __syncthreads();
    for (int off = SCAN_BS / 2; off > 0; off >>= 1) {
        if (threadIdx.x < off) sh[threadIdx.x] += sh[threadIdx.x + off];
        __syncthreads();
    }
    if (threadIdx.x == 0) partials[blockIdx.x] = sh[0];
}

// ---- 2b) exclusive scan of partials (single block, nb <= 256) --------------
__global__ void k_scanB(int* __restrict__ partials, int nb) {
    __shared__ int sh[SCAN_BS];
    int v = (threadIdx.x < nb) ? partials[threadIdx.x] : 0;
    sh[threadIdx.x] = v; __syncthreads();
    for (int off = 1; off < SCAN_BS; off <<= 1) {
        int t = (threadIdx.x >= off) ? sh[threadIdx.x - off] : 0;
        __syncthreads();
        sh[threadIdx.x] += t;
        __syncthreads();
    }
    if (threadIdx.x < nb) partials[threadIdx.x] = sh[threadIdx.x] - v;  // exclusive
}

// ---- 2c) full exclusive scan -> indptr (and cursor copy) -------------------
__global__ void k_scanC(const int* __restrict__ cnt, const int* __restrict__ partials,
                        int* __restrict__ indptr, int* __restrict__ cursor, int n) {
    __shared__ int sh[SCAN_BS];
    int base = blockIdx.x * SCAN_BS * SCAN_ITEMS + threadIdx.x * SCAN_ITEMS;
    int v[SCAN_ITEMS]; int s = 0;
#pragma unroll
    for (int k = 0; k < SCAN_ITEMS; ++k) { int i = base + k; v[k] = (i < n) ? cnt[i] : 0; s += v[k]; }
    sh[threadIdx.x] = s; __syncthreads();
    int mine = s;
    for (int off = 1; off < SCAN_BS; off <<= 1) {
        int t = (threadIdx.x >= off) ? sh[threadIdx.x - off] : 0;
        __syncthreads();
        sh[threadIdx.x] += t;
        __syncthreads();
    }
    int run = sh[threadIdx.x] - mine + partials[blockIdx.x];
#pragma unroll
    for (int k = 0; k < SCAN_ITEMS; ++k) {
        int i = base + k;
        if (i < n) { indptr[i] = run; cursor[i] = run; run += v[k]; }
    }
}

// ---- 3) dinv = (deg+1)^-0.5, invdeg = (deg+1)^-1 ---------------------------
__global__ void k_inv(const int* __restrict__ cnt, float* __restrict__ dinv,
                      float* __restrict__ invdeg, int n) {
    int i = blockIdx.x * blockDim.x + threadIdx.x;
    if (i < n) {
        float d = (float)cnt[i] + 1.0f;
        dinv[i]   = 1.0f / sqrtf(d);
        invdeg[i] = 1.0f / d;
    }
}

// ---- 4) scatter edges into CSR slots: csr[pos] = {src, norm} ---------------
__global__ void k_scatter(const int* __restrict__ src, const int* __restrict__ dst,
                          const float* __restrict__ dinv, int* __restrict__ cursor,
                          int2* __restrict__ csr, int ne) {
    int e = blockIdx.x * blockDim.x + threadIdx.x;
    if (e < ne) {
        int s = src[e], d = dst[e];
        int pos = atomicAdd(&cursor[d], 1);
        float w = dinv[s] * dinv[d];
        csr[pos] = make_int2(s, __float_as_int(w));
    }
}

// ---- 5) gather layer-1 pre-aggregation in 10-dim input space ---------------
//  z[v] = sum_e norm * x[src] + invdeg[v]*x[v]
__global__ void k_gather1(const int2* __restrict__ csr, const int* __restrict__ indptr,
                          const float* __restrict__ x, const float* __restrict__ invdeg,
                          float* __restrict__ z, int n, int ne) {
    int g = threadIdx.x >> 4, lane = threadIdx.x & 15;
    int v = blockIdx.x * 16 + g;
    if (v >= n) return;
    int beg = indptr[v];
    int end = (v == n - 1) ? ne : indptr[v + 1];
    if (lane < 10) {
        float acc = 0.f;
        for (int j = beg; j < end; ++j) {
            int2 en = csr[j];
            acc += __int_as_float(en.y) * x[(size_t)en.x * 10 + lane];
        }
        z[(size_t)v * 10 + lane] = acc + invdeg[v] * x[(size_t)v * 10 + lane];
    }
}

// ---- 6) fused: h1 = relu(z@W1 + b1);  m = h1@W2  (h1 never materialized) ---
__global__ void k_lin1(const float* __restrict__ z, const float* __restrict__ W1,
                       const float* __restrict__ b1, const float* __restrict__ W2,
                       float* __restrict__ m, int n) {
    __shared__ float W1s[640];
    __shared__ float W2s[2048];
    __shared__ float zs[4][10];
    __shared__ float ts[4][64];
    for (int i = threadIdx.x; i < 640; i += 256)  W1s[i] = W1[i];
    for (int i = threadIdx.x; i < 2048; i += 256) W2s[i] = W2[i];
    if (threadIdx.x < 40) {
        int nl = threadIdx.x / 10, k = threadIdx.x % 10;
        int v = blockIdx.x * 4 + nl;
        zs[nl][k] = (v < n) ? z[(size_t)v * 10 + k] : 0.f;
    }
    __syncthreads();
    int nl = threadIdx.x >> 6, f = threadIdx.x & 63;
    {
        float s = b1[f];
#pragma unroll
        for (int k = 0; k < 10; ++k) s += zs[nl][k] * W1s[k * 64 + f];
        ts[nl][f] = fmaxf(s, 0.f);
    }
    __syncthreads();
    if (threadIdx.x < 128) {
        int nl2 = threadIdx.x >> 5, o = threadIdx.x & 31;
        int v = blockIdx.x * 4 + nl2;
        if (v < n) {
            float s = 0.f;
#pragma unroll
            for (int f2 = 0; f2 < 64; ++f2) s += ts[nl2][f2] * W2s[f2 * 32 + o];
            m[(size_t)v * 32 + o] = s;
        }
    }
}

// ---- 7) gather layer-2 in 32-dim + self-loop + bias + relu -----------------
__global__ void k_gather2(const int2* __restrict__ csr, const int* __restrict__ indptr,
                          const float* __restrict__ m, const float* __restrict__ invdeg,
                          const float* __restrict__ b2, float* __restrict__ h2,
                          int n, int ne) {
    int g = threadIdx.x >> 5, f = threadIdx.x & 31;
    int v = blockIdx.x * 8 + g;
    if (v >= n) return;
    int beg = indptr[v];
    int end = (v == n - 1) ? ne : indptr[v + 1];
    float acc = 0.f;
    for (int j = beg; j < end; ++j) {
        int2 en = csr[j];
        acc += __int_as_float(en.y) * m[(size_t)en.x * 32 + f];
    }
    acc += invdeg[v] * m[(size_t)v * 32 + f] + b2[f];
    h2[(size_t)v * 32 + f] = fmaxf(acc, 0.f);
}

// ---- 8) per-graph pool (batch is sorted -> contiguous range) + FC + sigmoid
__global__ void k_poolfc(const float* __restrict__ h2, const int* __restrict__ batch,
                         const float* __restrict__ Wfc, const float* __restrict__ bfc,
                         float* __restrict__ out, int n) {
    int g = blockIdx.x;
    __shared__ int bounds[2];
    if (threadIdx.x < 2) {
        int target = g + threadIdx.x;  // lower_bound(batch, target)
        int lo = 0, hi = n;
        while (lo < hi) { int mid = (lo + hi) >> 1; if (batch[mid] < target) lo = mid + 1; else hi = mid; }
        bounds[threadIdx.x] = lo;
    }
    __syncthreads();
    int beg = bounds[0], end = bounds[1];
    int grp = threadIdx.x >> 5, f = threadIdx.x & 31;
    float acc = 0.f;
    for (int v = beg + grp; v < end; v += 8) acc += h2[(size_t)v * 32 + f];
    __shared__ float red[8][32];
    red[grp][f] = acc;
    __syncthreads();
    if (threadIdx.x < 32) {
        float s = 0.f;
#pragma unroll
        for (int r = 0; r < 8; ++r) s += red[r][threadIdx.x];
        float p = s * Wfc[threadIdx.x];
        for (int off = 16; off > 0; off >>= 1) p += __shfl_down(p, off, 32);
        if (threadIdx.x == 0) out[g] = 1.f / (1.f + expf(-(p + bfc[0])));
    }
}

extern "C" void kernel_launch(void* const* d_in, const int* in_sizes, int n_in,
                              void* d_out, int out_size, void* d_ws, size_t ws_size,
                              hipStream_t stream) {
    const int n  = in_sizes[0] / 10;   // 100000 nodes
    const int ne = in_sizes[1] / 2;    // 1600000 edges

    const float* x     = (const float*)d_in[0];
    const int*   ei    = (const int*)d_in[1];
    const int*   batch = (const int*)d_in[2];
    const float* W1    = (const float*)d_in[3];
    const float* b1    = (const float*)d_in[4];
    const float* W2    = (const float*)d_in[5];
    const float* b2    = (const float*)d_in[6];
    const float* Wfc   = (const float*)d_in[7];
    const float* bfc   = (const float*)d_in[8];
    const int* srcp = ei;
    const int* dstp = ei + ne;

    // workspace layout
    int*   cnt      = (int*)d_ws;                  // n
    int*   indptr   = cnt + n;                     // n
    int*   cursor   = indptr + n;                  // n
    int*   partials = cursor + n;                  // 256
    float* dinv     = (float*)(partials + 256);    // n
    float* invdeg   = dinv + n;                    // n
    int2*  csr      = (int2*)(invdeg + n);         // ne (8B-aligned: offset 5n+256 ints, even)
    float* z        = (float*)(csr + ne);          // n*10
    float* m        = z + (size_t)n * 10;          // n*32
    float* h2       = m + (size_t)n * 32;          // n*32

    const int nb = (n + SCAN_BS * SCAN_ITEMS - 1) / (SCAN_BS * SCAN_ITEMS);  // 98

    hipMemsetAsync(cnt, 0, (size_t)n * sizeof(int), stream);

    k_hist   <<<(ne + 255) / 256, 256, 0, stream>>>(dstp, cnt, ne);
    k_scanA  <<<nb, SCAN_BS, 0, stream>>>(cnt, partials, n);
    k_scanB  <<<1,  SCAN_BS, 0, stream>>>(partials, nb);
    k_scanC  <<<nb, SCAN_BS, 0, stream>>>(cnt, partials, indptr, cursor, n);
    k_inv    <<<(n + 255) / 256, 256, 0, stream>>>(cnt, dinv, invdeg, n);
    k_scatter<<<(ne + 255) / 256, 256, 0, stream>>>(srcp, dstp, dinv, cursor, csr, ne);
    k_gather1<<<(n + 15) / 16, 256, 0, stream>>>(csr, indptr, x, invdeg, z, n, ne);
    k_lin1   <<<(n + 3) / 4,   256, 0, stream>>>(z, W1, b1, W2, m, n);
    k_gather2<<<(n + 7) / 8,   256, 0, stream>>>(csr, indptr, m, invdeg, b2, h2, n, ne);
    k_poolfc <<<N_GRAPHS,      256, 0, stream>>>(h2, batch, Wfc, bfc, (float*)d_out, n);
}